// Round 5
// baseline (467.834 us; speedup 1.0000x reference)
//
#include <hip/hip_runtime.h>
#include <stdint.h>

// ---------------------------------------------------------------------------
// DkNN round 5: prefilter + exact refine.
//  Pass 1 (mfma_min): single-product Ah*Bh bf16 MFMA GEMM (K=256), 128x128
//    tiles, XCD-swizzled; epilogue stores per-(query, n-tile) min score and
//    a global packed (score,idx) atomicMin (the approximate minimum M).
//  Pass 2 (refine): per query, tiles with tilemin <= M + 0.04 are rescored
//    exactly in fp32 from the original X. Rigorous bound: bf16-rn rel err
//    <= 2^-8 per operand -> |d2_approx - d2_exact| <= 2*2^-7*|a||b| < 0.02,
//    so the true argmin's tile always qualifies (T = M + 2*0.02).
// ---------------------------------------------------------------------------

typedef __attribute__((ext_vector_type(8))) short short8;   // 8 bf16 = 4 VGPR
typedef __attribute__((ext_vector_type(4))) float float4v;  // MFMA C/D

static __device__ __forceinline__ unsigned short bf16_rn(float f) {
    unsigned int u = __float_as_uint(f);
    unsigned int r = (u + 0x7FFFu + ((u >> 16) & 1u)) >> 16;
    return (unsigned short)r;
}

static __device__ __forceinline__ void gload_lds16(const void* g, void* l) {
    __builtin_amdgcn_global_load_lds(
        (const __attribute__((address_space(1))) unsigned int*)g,
        (__attribute__((address_space(3))) unsigned int*)l, 16, 0, 0);
}

// Fused prep: blocks [0, Np/4) convert train rows (4/block, hi-bf16 + norm);
// blocks [Np/4, Np/4+Mp) prep one query row (normalize, center, hi-bf16,
// fp32 copy for refine, q2, gkey init).
__global__ void prep_all(const float* __restrict__ X, const float* __restrict__ x,
                         const float* __restrict__ center,
                         unsigned short* __restrict__ Bh, float* __restrict__ xn2,
                         unsigned short* __restrict__ Ah, float* __restrict__ xqf,
                         float* __restrict__ q2, unsigned long long* __restrict__ gkey,
                         int nb_train, int Np, int B, int Mp) {
    const int tid = threadIdx.x;
    const int tb = Np >> 2;
    if (blockIdx.x < (unsigned)tb) {
        int row = blockIdx.x * 4 + (tid >> 6);
        int lane = tid & 63;
        if (row >= nb_train) {
            *(ushort4*)(Bh + (size_t)row * 256 + lane * 4) = make_ushort4(0, 0, 0, 0);
            if (lane == 0) xn2[row] = 3.0e38f;
            return;
        }
        float4 v = ((const float4*)(X + (size_t)row * 256))[lane];
        ushort4 h;
        h.x = bf16_rn(v.x); h.y = bf16_rn(v.y);
        h.z = bf16_rn(v.z); h.w = bf16_rn(v.w);
        *(ushort4*)(Bh + (size_t)row * 256 + lane * 4) = h;
        float ss = v.x * v.x + v.y * v.y + v.z * v.z + v.w * v.w;
        #pragma unroll
        for (int s = 1; s < 64; s <<= 1) ss += __shfl_xor(ss, s);
        if (lane == 0) xn2[row] = ss;
        return;
    }
    int row = blockIdx.x - tb;
    if (row >= Mp) return;
    if (tid == 0) gkey[row] = ~0ULL;
    if (row >= B) {
        Ah[(size_t)row * 256 + tid] = 0;
        if (tid == 0) q2[row] = 0.0f;
        return;
    }
    float v = x[(size_t)row * 256 + tid];
    float ss = v * v;
    #pragma unroll
    for (int s = 1; s < 64; s <<= 1) ss += __shfl_xor(ss, s);
    __shared__ float partial[4];
    __shared__ float partial2[4];
    if ((tid & 63) == 0) partial[tid >> 6] = ss;
    __syncthreads();
    float tot = partial[0] + partial[1] + partial[2] + partial[3];
    float inv = 1.0f / sqrtf(tot);
    float val = v * inv - center[tid];
    Ah[(size_t)row * 256 + tid] = bf16_rn(val);
    xqf[(size_t)row * 256 + tid] = val;
    float ss2 = val * val;
    #pragma unroll
    for (int s = 1; s < 64; s <<= 1) ss2 += __shfl_xor(ss2, s);
    if ((tid & 63) == 0) partial2[tid >> 6] = ss2;
    __syncthreads();
    if (tid == 0) q2[row] = partial2[0] + partial2[1] + partial2[2] + partial2[3];
}

// Pass 1: 128x128 tile, 4 waves x 64x64 quadrants, K=256 in 4 steps of BK=64.
// XCD-swizzled 1D grid (xcd owns an n-slice, m fastest). Epilogue: packed
// argmin -> gkey (approx M) + per-(q, n-tile) min score -> tilemin.
__global__ __launch_bounds__(256, 4) void mfma_min(
    const unsigned short* __restrict__ Ah,  // Mp x 256 bf16
    const unsigned short* __restrict__ Bh,  // Np x 256 bf16
    const float* __restrict__ q2, const float* __restrict__ xn2,
    unsigned long long* __restrict__ gkey, float* __restrict__ tilemin,
    int nb_train, int B, int ntiles, int nper, int mtiles)
{
    __shared__ unsigned short As[128 * 64];   // [row][chunk ^ (row&7)] 16B chunks
    __shared__ unsigned short Bs[128 * 64];
    __shared__ unsigned long long skey[128];

    const int bid = blockIdx.x;
    const int xcd = bid & 7;
    const int s_  = bid >> 3;
    const int n_t = xcd * nper + (s_ / mtiles);
    const int m_t = s_ - (s_ / mtiles) * mtiles;
    if (n_t >= ntiles) return;
    const int mtile = m_t * 128;
    const int ntile = n_t * 128;

    const int tid  = threadIdx.x;
    const int wave = tid >> 6;
    const int lane = tid & 63;

    if (tid < 128) skey[tid] = ~0ULL;

    // staging role: waves 0,1 stage A rows [0:64),[64:128); waves 2,3 for B
    const int isB   = wave >> 1;
    const int Rwave = (wave & 1) * 64;
    const int lrow8  = lane >> 3;
    const int lchunk = lane & 7;
    const unsigned short* sbase = isB
        ? (Bh + (size_t)(ntile + Rwave + lrow8) * 256 + (size_t)((lchunk ^ lrow8) * 8))
        : (Ah + (size_t)(mtile + Rwave + lrow8) * 256 + (size_t)((lchunk ^ lrow8) * 8));
    unsigned short* lwave = (isB ? Bs : As) + Rwave * 64;

    // compute role: quadrant
    const int mq = (wave >> 1) * 64;
    const int nq = (wave & 1) * 64;
    const int lrow = lane & 15;
    const int kseg = lane >> 4;
    const int sw = lrow & 7;

    float4v acc[4][4];
    #pragma unroll
    for (int i = 0; i < 4; ++i)
        #pragma unroll
        for (int j = 0; j < 4; ++j)
            acc[i][j] = (float4v){0.f, 0.f, 0.f, 0.f};

    for (int s = 0; s < 4; ++s) {
        const unsigned short* g = sbase + s * 64;
        __syncthreads();
        #pragma unroll
        for (int q = 0; q < 8; ++q)
            gload_lds16(g + q * 2048, lwave + q * 512);
        __syncthreads();
        #pragma unroll
        for (int t = 0; t < 2; ++t) {
            const int wch = ((t * 4 + kseg) ^ sw) * 8;
            short8 a[4], b[4];
            #pragma unroll
            for (int i = 0; i < 4; ++i)
                a[i] = *(const short8*)&As[(mq + i * 16 + lrow) * 64 + wch];
            #pragma unroll
            for (int j = 0; j < 4; ++j)
                b[j] = *(const short8*)&Bs[(nq + j * 16 + lrow) * 64 + wch];
            #pragma unroll
            for (int i = 0; i < 4; ++i)
                #pragma unroll
                for (int j = 0; j < 4; ++j)
                    acc[i][j] = __builtin_amdgcn_mfma_f32_16x16x32_bf16(
                        a[i], b[j], acc[i][j], 0, 0, 0);
        }
    }

    float xnv[4];
    #pragma unroll
    for (int j = 0; j < 4; ++j)
        xnv[j] = xn2[ntile + nq + j * 16 + lrow];   // pads hold 3e38

    #pragma unroll
    for (int i = 0; i < 4; ++i) {
        #pragma unroll
        for (int r = 0; r < 4; ++r) {
            const int lm = mq + i * 16 + kseg * 4 + r;
            const int mi = mtile + lm;
            unsigned long long best = ~0ULL;
            if (mi < B) {
                float q2v = q2[mi];
                #pragma unroll
                for (int j = 0; j < 4; ++j) {
                    int t_ = ntile + nq + j * 16 + lrow;
                    float sc = fmaxf(q2v - 2.0f * acc[i][j][r] + xnv[j], 0.0f);
                    unsigned long long key =
                        ((unsigned long long)__float_as_uint(sc) << 32) | (unsigned int)t_;
                    best = (key < best) ? key : best;
                }
            }
            #pragma unroll
            for (int sft = 1; sft < 16; sft <<= 1) {
                unsigned long long o = __shfl_xor(best, sft);
                best = (o < best) ? o : best;
            }
            if (lrow == 0 && mi < B) atomicMin(&skey[lm], best);
        }
    }
    __syncthreads();
    if (tid < 128) {
        int mi = mtile + tid;
        if (mi < B) {
            unsigned long long k = skey[tid];
            atomicMin(gkey + mi, k);
            tilemin[(size_t)mi * ntiles + n_t] = __uint_as_float((unsigned)(k >> 32));
        }
    }
}

// Pass 2: one block per query. Scan tile-mins; rescore qualifying tiles
// exactly in fp32 from original X; emit exact packed argmin -> gbest.
__global__ __launch_bounds__(256) void refine(
    const float* __restrict__ xqf, const float* __restrict__ q2,
    const float* __restrict__ X, const float* __restrict__ xn2,
    const float* __restrict__ tilemin, const unsigned long long* __restrict__ gkey,
    unsigned long long* __restrict__ gbest, int ntiles, int nb_train)
{
    const int q = blockIdx.x;
    const int tid = threadIdx.x;
    __shared__ float sxq[256];
    __shared__ int list[800];
    __shared__ int lcnt;
    __shared__ unsigned long long wbest[4];
    if (tid == 0) lcnt = 0;
    sxq[tid] = xqf[(size_t)q * 256 + tid];
    __syncthreads();
    const float M = __uint_as_float((unsigned)(gkey[q] >> 32));
    const float T = M + 0.04f;
    const float* tm = tilemin + (size_t)q * ntiles;
    for (int i = tid; i < ntiles; i += 256)
        if (tm[i] <= T) { int s = atomicAdd(&lcnt, 1); list[s] = i; }
    __syncthreads();
    const int cnt = lcnt;
    const int p = tid >> 1, half = tid & 1;
    const float q2v = q2[q];
    unsigned long long best = ~0ULL;
    for (int li = 0; li < cnt; ++li) {
        int t = list[li] * 128 + p;
        if (t < nb_train) {
            const float4* xr = (const float4*)(X + (size_t)t * 256) + half * 32;
            const float4* qr = (const float4*)sxq + half * 32;
            float dot = 0.f;
            #pragma unroll
            for (int k = 0; k < 32; ++k) {
                float4 a = qr[k], b = xr[k];
                dot += a.x * b.x + a.y * b.y + a.z * b.z + a.w * b.w;
            }
            dot += __shfl_xor(dot, 1);
            if (half == 0) {
                float sc = fmaxf(q2v - 2.0f * dot + xn2[t], 0.0f);
                unsigned long long key =
                    ((unsigned long long)__float_as_uint(sc) << 32) | (unsigned)t;
                best = (key < best) ? key : best;
            }
        }
    }
    #pragma unroll
    for (int s = 1; s < 64; s <<= 1) {
        unsigned long long o = __shfl_xor(best, s);
        best = (o < best) ? o : best;
    }
    if ((tid & 63) == 0) wbest[tid >> 6] = best;
    __syncthreads();
    if (tid == 0) {
        unsigned long long b = wbest[0];
        b = (wbest[1] < b) ? wbest[1] : b;
        b = (wbest[2] < b) ? wbest[2] : b;
        b = (wbest[3] < b) ? wbest[3] : b;
        gbest[q] = b;
    }
}

// One wave per query: 75 gathers across lanes, ballot bincount, bisect p-values.
__global__ void classify(const unsigned long long* __restrict__ gbest,
                         const int* __restrict__ labels,
                         const int* __restrict__ nbr,
                         const int* __restrict__ cali,
                         float* __restrict__ out,
                         int knm1, int nb_cali, int B)
{
    int q = blockIdx.x * 4 + (threadIdx.x >> 6);
    int lane = threadIdx.x & 63;
    if (q >= B) return;
    int closest = (int)(gbest[q] & 0xFFFFFFFFULL);
    int K = knm1 + 1;   // 75
    int lbl0 = -1, lbl1 = -1;
    if (lane < K) {
        int idx = (lane == 0) ? closest : nbr[(size_t)closest * knm1 + (lane - 1)];
        lbl0 = labels[idx];
    }
    int j2 = lane + 64;
    if (j2 < K) {
        int idx = nbr[(size_t)closest * knm1 + (j2 - 1)];
        lbl1 = labels[idx];
    }
    int bestc = 0, bestp = -1;
    #pragma unroll
    for (int c = 0; c < 10; ++c) {
        int cnt = __popcll(__ballot(lbl0 == c)) + __popcll(__ballot(lbl1 == c));
        int v = K - cnt;
        int lo = 0, hi = nb_cali;
        while (lo < hi) {                 // bisect_left
            int mid = (lo + hi) >> 1;
            if (cali[mid] < v) lo = mid + 1; else hi = mid;
        }
        int p = nb_cali - lo;
        if (p > bestp) { bestp = p; bestc = c; }
    }
    float pv = (float)bestp / (float)nb_cali;
    if (lane < 10)
        out[(size_t)q * 10 + lane] = (lane == bestc) ? pv : 0.0f;
}

extern "C" void kernel_launch(void* const* d_in, const int* in_sizes, int n_in,
                              void* d_out, int out_size, void* d_ws, size_t ws_size,
                              hipStream_t stream) {
    const float* x      = (const float*)d_in[0];
    const float* X      = (const float*)d_in[1];
    const float* center = (const float*)d_in[2];
    const int* labels   = (const int*)d_in[3];
    const int* nbr      = (const int*)d_in[4];
    const int* cali     = (const int*)d_in[5];
    float* out = (float*)d_out;

    const int d        = in_sizes[2];              // 256
    const int B        = in_sizes[0] / d;          // 1024
    const int nb_train = in_sizes[3];              // 100000
    const int knm1     = in_sizes[4] / nb_train;   // 74
    const int nb_cali  = in_sizes[5];              // 1000

    const int Mp = (B + 127) & ~127;               // 1024
    const int Np = (nb_train + 127) & ~127;        // 100096
    const int ntiles = Np / 128;                   // 782
    const int mtiles = Mp / 128;                   // 8
    const int nper   = (ntiles + 7) / 8;           // 98

    char* ws = (char*)d_ws;
    size_t off = 0;
    unsigned long long* gkey  = (unsigned long long*)(ws + off); off += (size_t)Mp * 8;
    unsigned long long* gbest = (unsigned long long*)(ws + off); off += (size_t)Mp * 8;
    float* q2   = (float*)(ws + off); off += (size_t)Mp * 4;
    float* xqf  = (float*)(ws + off); off += (size_t)Mp * 256 * 4;
    float* xn2  = (float*)(ws + off); off += (size_t)Np * 4;
    float* tmin = (float*)(ws + off); off += (size_t)Mp * ntiles * 4;
    unsigned short* Ah = (unsigned short*)(ws + off); off += (size_t)Mp * 256 * 2;
    unsigned short* Bh = (unsigned short*)(ws + off); off += (size_t)Np * 256 * 2;

    prep_all<<<Np / 4 + Mp, 256, 0, stream>>>(X, x, center, Bh, xn2,
                                              Ah, xqf, q2, gkey,
                                              nb_train, Np, B, Mp);
    mfma_min<<<8 * nper * mtiles, 256, 0, stream>>>(
        Ah, Bh, q2, xn2, gkey, tmin, nb_train, B, ntiles, nper, mtiles);
    refine<<<B, 256, 0, stream>>>(xqf, q2, X, xn2, tmin, gkey, gbest,
                                  ntiles, nb_train);
    classify<<<(B + 3) / 4, 256, 0, stream>>>(gbest, labels, nbr, cali, out,
                                              knm1, nb_cali, B);
}